// Round 2
// baseline (437.409 us; speedup 1.0000x reference)
//
#include <hip/hip_runtime.h>
#include <math.h>

#define MAXDEG 20
#define NM 21               // m = 0..20
#define RANK 256
#define PPB 8               // points per block
#define NSLOT (2*PPB)       // 16 (point,dir) table slots
#define S_STRIDE 446        // words per slot: even (b64 align), 446%32=30
#define HDRS 65             // header stride (odd -> conflict-free slot-parallel reads)

// Storage layout inside a slot (441 used words of S_STRIDE):
//   m=1..20 pair-columns first: base cb(m) = (m-1)*(42-m) (always even),
//     entry for l (l=m..20): [cb + 2*(l-m)] = Y_{l,+m}, [cb + 2*(l-m)+1] = Y_{l,-m}
//   m=0 column at [420 + l], l=0..20.

__device__ __forceinline__ int remap_idx(int k) {
  // flax index k = l*(l+1)+m  ->  storage index
  int l = (int)sqrtf((float)k);
  if (l*l > k) --l;
  if ((l+1)*(l+1) <= k) ++l;
  int m = k - l*(l+1);
  int am = m < 0 ? -m : m;
  if (am == 0) return 420 + l;
  return (am-1)*(42-am) + 2*(l-am) + (m < 0 ? 1 : 0);
}

__global__ __launch_bounds__(256, 4)
void sh_fused(const float* __restrict__ coords,
              const int* __restrict__ rand_i,
              const int* __restrict__ rand_j,
              float* __restrict__ out, int N) {
  __shared__ float2 s_ab[231];              // normalized-recurrence coeffs (a,b) per tri(l,m)
  __shared__ float  s_hdr[NSLOT * HDRS];    // per slot: [0..20]=cos(m phi) [21..41]=sin [42..62]=Pmm [63]=x
  __shared__ float  s_tab[NSLOT * S_STRIDE];

  const int t  = threadIdx.x;
  const int n0 = blockIdx.x * PPB;

  // ---- remap gather indices (once, registers): thread t -> ranks 4*(t&63)..+3 ----
  const int rg = t & 63;
  int rI[4], rJ[4];
  {
    int4 a = ((const int4*)rand_i)[rg];
    int4 b = ((const int4*)rand_j)[rg];
    rI[0]=remap_idx(a.x); rI[1]=remap_idx(a.y); rI[2]=remap_idx(a.z); rI[3]=remap_idx(a.w);
    rJ[0]=remap_idx(b.x); rJ[1]=remap_idx(b.y); rJ[2]=remap_idx(b.z); rJ[3]=remap_idx(b.w);
  }

  // ---- recurrence coefficient table (tri index -> (l,m)) ----
  if (t < 231) {
    int l = (int)((sqrtf(8.0f*(float)t + 1.0f) - 1.0f) * 0.5f);
    if (l*(l+1)/2 > t) --l;
    if ((l+1)*(l+2)/2 <= t) ++l;
    int m = t - l*(l+1)/2;
    float a = 0.f, b = 0.f;
    if (l >= m + 2) {
      float l2 = (float)(l*l), m2 = (float)(m*m);
      float inv = 1.0f / (l2 - m2);
      a = sqrtf((4.f*l2 - 1.f) * inv);
      b = sqrtf((2.f*(float)l + 1.f) * ((float)((l-1)*(l-1)) - m2)
                / (2.f*(float)l - 3.f) * inv);
    }
    s_ab[t] = make_float2(a, b);
  }

  // ---- header: fully parallel closed forms. slot = t&15, m-tasks strided 16 ----
  {
    const int slot = t & 15;
    const int p = slot >> 1, d = slot & 1;
    int n = n0 + p; if (n >= N) n = N - 1;
    const float* c = coords + (size_t)n * 6 + d * 3;
    float cx = c[0], cy = c[1], cz = c[2];
    float x = cz * rsqrtf(cx*cx + cy*cy + cz*cz);   // cos(inclination)
    x = fminf(1.f, fmaxf(-1.f, x));
    float s = sqrtf(fmaxf(0.f, 1.f - x*x));          // sin(inclination) >= 0
    s = fmaxf(s, 1e-30f);                            // keep log2f finite (m=0 -> 0*log=0)
    float phi = atan2f(cy, cx);                      // atan2(0,0)=0 matches jnp
    float l2s = log2f(s);
    float* h = s_hdr + slot * HDRS;
    if ((t >> 4) == 0) h[63] = x;
    for (int m = (t >> 4); m < NM; m += 16) {
      float sv, cv;
      __sincosf((float)m * phi, &sv, &cv);
      // K_m = sqrt(1/4pi) * sqrt(prod (2k+1)/(2k)) * sqrt2(m>0) * (-1)^m  (CS phase)
      float prod = 1.f;
      for (int k = 1; k <= m; ++k) prod *= (2.f*(float)k + 1.f) / (2.f*(float)k);
      float Km = 0.28209479177387814f * sqrtf(prod);
      if (m > 0) { Km *= 1.41421356237309515f; if (m & 1) Km = -Km; }
      float pmm = Km * exp2f((float)m * l2s);        // K_m * s^m
      h[m] = cv; h[21 + m] = sv; h[42 + m] = pmm;
    }
  }
  __syncthreads();

  // ---- phase 1: fill Y tables. task = (m, point), both dirs per task ----
  if (t < NM * PPB) {   // 168 tasks
    const int m = t >> 3, p = t & 7;
    const float* h0 = s_hdr + (2*p) * HDRS;
    const float* h1 = h0 + HDRS;
    float x0 = h0[63],   x1 = h1[63];
    float cm0 = h0[m],   sm0 = h0[21+m], pm0 = h0[42+m];
    float cm1 = h1[m],   sm1 = h1[21+m], pm1 = h1[42+m];
    float* slot0 = s_tab + (2*p) * S_STRIDE;
    float* slot1 = slot0 + S_STRIDE;
    if (m == 0) {
      float* c0 = slot0 + 420; float* c1 = slot1 + 420;
      float q0 = pm0, q1 = pm1;
      c0[0] = q0; c1[0] = q1;
      float p0 = 1.7320508075688772f * x0 * q0;      // sqrt(3)*x*Y00
      float p1 = 1.7320508075688772f * x1 * q1;
      c0[1] = p0; c1[1] = p1;
      int ti = 3;                                    // tri(2,0)
      for (int l = 2; l <= MAXDEG; ++l) {
        float2 ab = s_ab[ti];
        float v0 = ab.x * (x0 * p0) - ab.y * q0;
        float v1 = ab.x * (x1 * p1) - ab.y * q1;
        q0 = p0; p0 = v0; q1 = p1; p1 = v1;
        c0[l] = v0; c1[l] = v1;
        ti += l + 1;
      }
    } else {
      const int cb = (m-1)*(42-m);
      float2* c0 = (float2*)(slot0 + cb);
      float2* c1 = (float2*)(slot1 + cb);
      c0[0] = make_float2(pm0*cm0, pm0*sm0);         // l = m
      c1[0] = make_float2(pm1*cm1, pm1*sm1);
      if (m < MAXDEG) {
        float q0 = pm0, q1 = pm1;
        float se = sqrtf(2.f*(float)m + 3.f);
        float p0 = se * x0 * pm0, p1 = se * x1 * pm1; // l = m+1
        c0[1] = make_float2(p0*cm0, p0*sm0);
        c1[1] = make_float2(p1*cm1, p1*sm1);
        int ti = (m+2)*(m+3)/2 + m;                  // tri(m+2, m)
        int idx = 2;
        for (int l = m+2; l <= MAXDEG; ++l) {
          float2 ab = s_ab[ti];
          float v0 = ab.x * (x0 * p0) - ab.y * q0;
          float v1 = ab.x * (x1 * p1) - ab.y * q1;
          q0 = p0; p0 = v0; q1 = p1; p1 = v1;
          c0[idx] = make_float2(v0*cm0, v0*sm0);
          c1[idx] = make_float2(v1*cm1, v1*sm1);
          ++idx; ti += l + 1;
        }
      }
    }
  }
  __syncthreads();

  // ---- phase 2: gathered products, float4 coalesced stores ----
  const int pi = t >> 6;                  // wave id = point sub-index
  for (int k = 0; k < PPB/4; ++k) {
    const int p = pi + 4*k;
    const float* Y1 = s_tab + (2*p) * S_STRIDE;
    const float* Y2 = Y1 + S_STRIDE;
    float4 v;
    v.x = Y1[rI[0]] * Y2[rJ[0]];
    v.y = Y1[rI[1]] * Y2[rJ[1]];
    v.z = Y1[rI[2]] * Y2[rJ[2]];
    v.w = Y1[rI[3]] * Y2[rJ[3]];
    const int n = n0 + p;
    if (n < N) *(float4*)(out + (size_t)n * RANK + 4*rg) = v;
  }
}

extern "C" void kernel_launch(void* const* d_in, const int* in_sizes, int n_in,
                              void* d_out, int out_size, void* d_ws, size_t ws_size,
                              hipStream_t stream) {
  const float* coords = (const float*)d_in[0];
  const int*   rand_i = (const int*)d_in[1];
  const int*   rand_j = (const int*)d_in[2];
  float*       out    = (float*)d_out;
  const int N = in_sizes[0] / 6;
  const int grid = (N + PPB - 1) / PPB;
  sh_fused<<<grid, 256, 0, stream>>>(coords, rand_i, rand_j, out, N);
}